// Round 23
// baseline (106.138 us; speedup 1.0000x reference)
//
#include <hip/hip_runtime.h>
#include <hip/hip_bf16.h>

// ---------------------------------------------------------------------------
// Self-attention MH: B=2, QL=KL=2048, D=1024, H=16, E=64.
// R23: fuse x f32->bf16 into gemm_qkv WITHOUT reg-staging (R18's mistake):
//      A staged as f32 via async global_load_lds (BK=32, 24KB LDS, 3/CU),
//      converted to bf16 at fragment-read (2x ds_read_b128 + 4 packs).
//      cvt_all shrinks to weights+lens. attn / gemm_out(dbuf) as R22 (best).
// ---------------------------------------------------------------------------

typedef __bf16 bf16x8 __attribute__((ext_vector_type(8)));
typedef float f32x4 __attribute__((ext_vector_type(4)));
typedef unsigned int u32x4 __attribute__((ext_vector_type(4)));
typedef unsigned short u16;
typedef unsigned int u32;

#define GLOBAL_AS __attribute__((address_space(1)))
#define LDS_AS __attribute__((address_space(3)))

static __device__ __forceinline__ u16 f2bf(float f) {
    __hip_bfloat16 h = __float2bfloat16(f);
    return __builtin_bit_cast(u16, h);
}
static __device__ __forceinline__ u32 pack2bf(float a, float b) {
    return (u32)f2bf(a) | ((u32)f2bf(b) << 16);
}
static __device__ __forceinline__ float exp2_hw(float x) {
    return __builtin_amdgcn_exp2f(x);   // v_exp_f32 (base-2)
}

// --------------- weights f32 -> bf16 (+ padding-length blocks) -------------
__global__ void cvt_all(const float* __restrict__ wq_f, const float* __restrict__ wk_f,
                        const float* __restrict__ wv_f, const float* __restrict__ wo_f,
                        u16* __restrict__ wq, u16* __restrict__ wk,
                        u16* __restrict__ wv, u16* __restrict__ wo,
                        const int* __restrict__ kpm, int* __restrict__ lens) {
    int blk = blockIdx.x;
    if (blk >= 4096) {
        const int b = blk - 4096, tid = threadIdx.x;
        int cnt = 0;
        #pragma unroll
        for (int i = 0; i < 8; ++i) cnt += (kpm[b * 2048 + i * 256 + tid] == 0) ? 1 : 0;
        #pragma unroll
        for (int off = 32; off; off >>= 1) cnt += __shfl_down(cnt, off);
        __shared__ int wsum[4];
        if ((tid & 63) == 0) wsum[tid >> 6] = cnt;
        __syncthreads();
        if (tid == 0) lens[b] = wsum[0] + wsum[1] + wsum[2] + wsum[3];
        return;
    }
    int wsel = blk >> 10;
    int i = (blk & 1023) * 256 + threadIdx.x;
    const float* s; u16* d;
    if (wsel == 0)      { s = wq_f; d = wq; }
    else if (wsel == 1) { s = wk_f; d = wk; }
    else if (wsel == 2) { s = wv_f; d = wv; }
    else                { s = wo_f; d = wo; }
    float4 v = reinterpret_cast<const float4*>(s)[i];
    ushort4 o;
    o.x = f2bf(v.x); o.y = f2bf(v.y); o.z = f2bf(v.z); o.w = f2bf(v.w);
    reinterpret_cast<ushort4*>(d)[i] = o;
}

// ------------------------------ GEMM bodies --------------------------------
// Single-buffer BK=64 bf16 body (kept for reference/unused) and dbuf variant
// for gemm_out (as R22).
template<int OUT_F32, int BM, int BN>
__device__ __forceinline__
void gemm_body_dbuf(const u16* __restrict__ A, const u16* __restrict__ Bw,
                    const float* __restrict__ bias, void* __restrict__ Cout,
                    int N, int K, float scale, int bx, int by) {
    constexpr int MREP = BM / 32, NREP = BN / 32;
    constexpr int ACH = BM / 8, TCH = ACH + BN / 8;
    constexpr int CPW = TCH / 4;
    __shared__ __attribute__((aligned(16))) u16 aS[2][BM * 64];
    __shared__ __attribute__((aligned(16))) u16 bS[2][BN * 64];
    const int tid = threadIdx.x, wave = tid >> 6, lane = tid & 63;
    const int m0 = by * BM, n0 = bx * BN;
    const int wr = wave >> 1, wc = wave & 1;
    const int fr = lane & 15, fq = lane >> 4;
    const int swz_col = (((lane & 7) ^ (lane >> 3)) * 8);
    const int rsw = (fr & 7) << 3;

    f32x4 acc[MREP][NREP] = {};

    auto stage = [&](int k0, int buf) {
        #pragma unroll
        for (int i = 0; i < CPW; ++i) {
            int chunk = wave * CPW + i;
            const u16* gsrc; u16* ldst;
            if (chunk < ACH) {
                int row = chunk * 8 + (lane >> 3);
                gsrc = A + (size_t)(m0 + row) * K + k0 + swz_col;
                ldst = &aS[buf][chunk * 512];
            } else {
                int row = (chunk - ACH) * 8 + (lane >> 3);
                gsrc = Bw + (size_t)(n0 + row) * K + k0 + swz_col;
                ldst = &bS[buf][(chunk - ACH) * 512];
            }
            __builtin_amdgcn_global_load_lds((GLOBAL_AS void*)gsrc,
                                             (LDS_AS void*)ldst, 16, 0, 0);
        }
    };

    stage(0, 0);
    __syncthreads();
    int cur = 0;

    for (int k0 = 0; k0 < K; k0 += 64) {
        if (k0 + 64 < K) stage(k0 + 64, cur ^ 1);

        bf16x8 af[MREP][2], bfr[NREP][2];
        #pragma unroll
        for (int m = 0; m < MREP; ++m)
            #pragma unroll
            for (int h = 0; h < 2; ++h)
                af[m][h] = *reinterpret_cast<const bf16x8*>(
                    &aS[cur][(wr * (BM / 2) + m * 16 + fr) * 64 + ((h * 32 + fq * 8) ^ rsw)]);
        #pragma unroll
        for (int n = 0; n < NREP; ++n)
            #pragma unroll
            for (int h = 0; h < 2; ++h)
                bfr[n][h] = *reinterpret_cast<const bf16x8*>(
                    &bS[cur][(wc * (BN / 2) + n * 16 + fr) * 64 + ((h * 32 + fq * 8) ^ rsw)]);
        __builtin_amdgcn_s_setprio(1);
        #pragma unroll
        for (int m = 0; m < MREP; ++m)
            #pragma unroll
            for (int n = 0; n < NREP; ++n) {
                acc[m][n] = __builtin_amdgcn_mfma_f32_16x16x32_bf16(af[m][0], bfr[n][0], acc[m][n], 0, 0, 0);
                acc[m][n] = __builtin_amdgcn_mfma_f32_16x16x32_bf16(af[m][1], bfr[n][1], acc[m][n], 0, 0, 0);
            }
        __builtin_amdgcn_s_setprio(0);
        __syncthreads();
        cur ^= 1;
    }

    #pragma unroll
    for (int n = 0; n < NREP; ++n) {
        int col = n0 + wc * (BN / 2) + n * 16 + fr;
        float bv = bias[col];
        #pragma unroll
        for (int m = 0; m < MREP; ++m) {
            #pragma unroll
            for (int j = 0; j < 4; ++j) {
                int row = m0 + wr * (BM / 2) + m * 16 + fq * 4 + j;
                float v = (acc[m][n][j] + bv) * scale;
                if (OUT_F32)
                    reinterpret_cast<float*>(Cout)[(size_t)row * N + col] = v;
                else
                    reinterpret_cast<u16*>(Cout)[(size_t)row * N + col] = f2bf(v);
            }
        }
    }
}

// Fused Q/K/V projection with f32 A staged via ASYNC global_load_lds (BK=32):
// aSf [128][32] f32 (16KB, granule^(row&7) swizzle — conflict-free since row
// stride = exactly 32 banks), bS [128][32] bf16 (8KB, granule^((row>>2)&3)).
// A converted to bf16 at fragment-read (2x ds_read_b128 + 4 pack2bf). 24KB
// LDS -> 3 blocks/CU, grid 768 exactly resident. Q pre-scaled by log2e/32.
__global__ __launch_bounds__(256, 3)
void gemm_qkv(const float* __restrict__ xq_f, const float* __restrict__ xk_f,
              const u16* __restrict__ wq, const u16* __restrict__ wk,
              const u16* __restrict__ wv,
              const float* __restrict__ bq, const float* __restrict__ bk,
              const float* __restrict__ bv,
              u16* __restrict__ qb, u16* __restrict__ kb, u16* __restrict__ vb) {
    const int id = blockIdx.x;
    const int g = id & 7, s = id >> 3;          // XCD, slot 0..95
    const int z = s >> 5;                        // 0..2 (CU-mates differ in z)
    const int xl = (s >> 3) & 3, byl = s & 7;
    const int bx = (g & 1) * 4 + xl;
    const int by = (g >> 1) * 8 + byl;
    const float* Af = (z == 0) ? xq_f : xk_f;
    const u16* W = (z == 0) ? wq : (z == 1) ? wk : wv;
    const float* bias = (z == 0) ? bq : (z == 1) ? bk : bv;
    u16* C = (z == 0) ? qb : (z == 1) ? kb : vb;
    const float scale = (z == 0) ? 0.0450842200f : 1.0f;   // log2e/32

    __shared__ __attribute__((aligned(16))) float aSf[128 * 32];  // 16 KB
    __shared__ __attribute__((aligned(16))) u16 bS[128 * 32];     // 8 KB
    const int tid = threadIdx.x, wave = tid >> 6, lane = tid & 63;
    const int m0 = by * 128, n0 = bx * 128;
    const int wr = wave >> 1, wc = wave & 1;
    const int fr = lane & 15, fq = lane >> 4;
    const int a_sub = lane >> 3, a_g = lane & 7;   // A chunk: 8 rows x 8 granules
    const int b_sub = lane >> 2, b_g = lane & 3;   // B chunk: 16 rows x 4 granules

    f32x4 acc[4][4] = {};

    for (int k0 = 0; k0 < 1024; k0 += 32) {
        // 24 chunks: A 0..15 (1KB = 8 rows x 32 f32), B 16..23 (1KB = 16 rows x 32 u16)
        #pragma unroll
        for (int i = 0; i < 6; ++i) {
            int chunk = wave * 6 + i;
            if (chunk < 16) {
                int row = chunk * 8 + a_sub;
                const float* gsrc = Af + (size_t)(m0 + row) * 1024 + k0 + ((a_g ^ (row & 7)) * 4);
                __builtin_amdgcn_global_load_lds((GLOBAL_AS void*)gsrc,
                    (LDS_AS void*)(aSf + chunk * 256 + lane * 4), 16, 0, 0);
            } else {
                int bc = chunk - 16;
                int row = bc * 16 + b_sub;
                const u16* gsrc = W + (size_t)(n0 + row) * 1024 + k0 + ((b_g ^ ((row >> 2) & 3)) * 8);
                __builtin_amdgcn_global_load_lds((GLOBAL_AS void*)gsrc,
                    (LDS_AS void*)(bS + bc * 512 + lane * 8), 16, 0, 0);
            }
        }
        __syncthreads();

        // A fragments: read f32, convert to bf16 in-register
        bf16x8 af[4];
        #pragma unroll
        for (int m = 0; m < 4; ++m) {
            int row = wr * 64 + m * 16 + fr;
            int r7 = row & 7;
            f32x4 a0 = *reinterpret_cast<const f32x4*>(&aSf[row * 32 + (((2 * fq) ^ r7) * 4)]);
            f32x4 a1 = *reinterpret_cast<const f32x4*>(&aSf[row * 32 + (((2 * fq + 1) ^ r7) * 4)]);
            u32x4 w;
            w[0] = pack2bf(a0[0], a0[1]); w[1] = pack2bf(a0[2], a0[3]);
            w[2] = pack2bf(a1[0], a1[1]); w[3] = pack2bf(a1[2], a1[3]);
            af[m] = __builtin_bit_cast(bf16x8, w);
        }
        bf16x8 bfr[4];
        #pragma unroll
        for (int n = 0; n < 4; ++n) {
            int row = wc * 64 + n * 16 + fr;
            bfr[n] = *reinterpret_cast<const bf16x8*>(
                &bS[row * 32 + ((fq ^ ((row >> 2) & 3)) * 8)]);
        }
        __builtin_amdgcn_s_setprio(1);
        #pragma unroll
        for (int m = 0; m < 4; ++m)
            #pragma unroll
            for (int n = 0; n < 4; ++n)
                acc[m][n] = __builtin_amdgcn_mfma_f32_16x16x32_bf16(af[m], bfr[n], acc[m][n], 0, 0, 0);
        __builtin_amdgcn_s_setprio(0);
        __syncthreads();
    }

    #pragma unroll
    for (int n = 0; n < 4; ++n) {
        int col = n0 + wc * 64 + n * 16 + fr;
        float bv = bias[col];
        #pragma unroll
        for (int m = 0; m < 4; ++m) {
            #pragma unroll
            for (int j = 0; j < 4; ++j) {
                int row = m0 + wr * 64 + m * 16 + fq * 4 + j;
                float v = (acc[m][n][j] + bv) * scale;
                C[(size_t)row * 1024 + col] = f2bf(v);
            }
        }
    }
}

// Out projection: 64x128 tiles, linear grid 512, 2x4 XCD split, dbuf (R22).
__global__ __launch_bounds__(256, 2)
void gemm_out(const u16* __restrict__ A, const u16* __restrict__ Bw,
              const float* __restrict__ bias, float* __restrict__ Cout) {
    const int id = blockIdx.x;
    const int g = id & 7, s = id >> 3;          // slot 0..63
    const int xl = s & 3, byl = s >> 2;         // byl 0..15
    const int bx = (g & 1) * 4 + xl;
    const int by = (g >> 1) * 16 + byl;
    gemm_body_dbuf<1, 64, 128>(A, Bw, bias, Cout, 1024, 1024, 1.0f, bx, by);
}

// ------------------------------ flash attention ----------------------------
// (byte-identical to R21/R22 — grid 1024, 2x2 wave decomposition, swapped
// QK^T, in-register P, fixed-base exp2 softmax, l via MFMA-ones, padded
// combine scratch)
__global__ __launch_bounds__(256, 4)
void attn_fwd(const u16* __restrict__ Qb, const u16* __restrict__ Kb,
              const u16* __restrict__ Vb, const int* __restrict__ lens,
              u16* __restrict__ Ob) {
    __shared__ __attribute__((aligned(16))) u16 Ks[2][64 * 64];
    __shared__ __attribute__((aligned(16))) u16 Vts[2][64 * 64];
    const int tid = threadIdx.x, wave = tid >> 6, lane = tid & 63;
    const int id = blockIdx.x;
    const int bh = (id & 7) * 4 + ((id >> 3) & 3);
    const int k5 = id >> 5;
    const int g = k5 >> 3, x8 = k5 & 7;
    const int qt = (g == 0) ? x8 : (g == 1) ? 31 - x8 : (g == 2) ? 16 + x8 : 15 - x8;
    const int b = bh >> 4, h = bh & 15;
    const int fr = lane & 15, fq = lane >> 4;
    const int t = wave >> 1;                    // k-half team
    const int u = wave & 1;                     // q-half
    const int qbase = qt * 64 + u * 32;
    const int len = lens[b];
    const int nt = min(qt + 1, (len + 63) >> 6);

    bf16x8 qa[2][2];
    #pragma unroll
    for (int gq = 0; gq < 2; ++gq) {
        const size_t qoff = (size_t)(b * 2048 + qbase + gq * 16 + fr) * 1024 + h * 64 + fq * 8;
        qa[gq][0] = *reinterpret_cast<const bf16x8*>(Qb + qoff);
        qa[gq][1] = *reinterpret_cast<const bf16x8*>(Qb + qoff + 32);
    }

    bf16x8 ones;
    #pragma unroll
    for (int i = 0; i < 8; ++i) ones[i] = __builtin_bit_cast(__bf16, (u16)0x3F80);

    f32x4 o_acc[2][4] = {};
    f32x4 lacc[2] = {};

    const int e8 = tid >> 5;
    const int c2 = tid & 31;
    const int kp = 2 * c2;
    const int vhalf = kp >> 5, r5 = kp & 31;
    const int fqv = r5 >> 3, nv = (r5 >> 2) & 1, jv = r5 & 3;
    const int k_src = vhalf * 32 + nv * 16 + fqv * 4 + jv;
    const int kswz_col = (((lane & 7) ^ (lane >> 3)) * 8);

    auto issue_K = [&](int kt, int buf) {
        #pragma unroll
        for (int i = 0; i < 2; ++i) {
            int chunk = wave * 2 + i;
            int krow = chunk * 8 + (lane >> 3);
            const u16* gk = Kb + (size_t)(b * 2048 + kt * 64 + krow) * 1024 + h * 64 + kswz_col;
            __builtin_amdgcn_global_load_lds((GLOBAL_AS void*)gk,
                                             (LDS_AS void*)(&Ks[buf][chunk * 512]), 16, 0, 0);
        }
    };
    auto load_V = [&](int kt, ushort4* r) {
        const u16* b1 = Vb + (size_t)(b * 2048 + kt * 64 + k_src) * 1024 + h * 64 + e8 * 8;
        r[0] = reinterpret_cast<const ushort4*>(b1)[0];
        r[1] = reinterpret_cast<const ushort4*>(b1 + 4)[0];
        r[2] = reinterpret_cast<const ushort4*>(b1 + 1024)[0];        // k_src+1
        r[3] = reinterpret_cast<const ushort4*>(b1 + 1024 + 4)[0];
    };
    auto write_V = [&](const ushort4* r, int buf) {
        u32* vbase = reinterpret_cast<u32*>(&Vts[buf][0]);
        const u16* lo16 = reinterpret_cast<const u16*>(&r[0]);
        const u16* hi16 = reinterpret_cast<const u16*>(&r[2]);
        #pragma unroll
        for (int i = 0; i < 8; ++i) {
            u32 w = (u32)lo16[i] | ((u32)hi16[i] << 16);
            vbase[(e8 * 8 + i) * 32 + (c2 ^ (i << 2))] = w;
        }
    };

    {
        ushort4 vr[4];
        issue_K(0, 0);
        load_V(0, vr);
        write_V(vr, 0);
    }
    __syncthreads();

    for (int kt = 0; kt < nt; ++kt) {
        const int k0 = kt * 64;
        const int kbase = k0 + t * 32;
        const int cur = kt & 1, nxt = cur ^ 1;
        const bool has_next = (kt + 1 < nt);

        ushort4 vr[4];
        if (has_next) {
            issue_K(kt + 1, nxt);
            load_V(kt + 1, vr);
        }

        f32x4 s[2][2] = {};
        __builtin_amdgcn_s_setprio(1);
        #pragma unroll
        for (int kq2 = 0; kq2 < 2; ++kq2) {
            int kr = t * 32 + kq2 * 16 + fr;
            int sw = (fr & 7) << 3;
            bf16x8 kb0 = *reinterpret_cast<const bf16x8*>(&Ks[cur][kr * 64 + ((fq * 8) ^ sw)]);
            bf16x8 kb1 = *reinterpret_cast<const bf16x8*>(&Ks[cur][kr * 64 + ((32 + fq * 8) ^ sw)]);
            #pragma unroll
            for (int gq = 0; gq < 2; ++gq) {
                s[kq2][gq] = __builtin_amdgcn_mfma_f32_16x16x32_bf16(kb0, qa[gq][0], s[kq2][gq], 0, 0, 0);
                s[kq2][gq] = __builtin_amdgcn_mfma_f32_16x16x32_bf16(kb1, qa[gq][1], s[kq2][gq], 0, 0, 0);
            }
        }
        __builtin_amdgcn_s_setprio(0);

        const bool fullt = (kbase + 31 <= qbase) && (kbase + 32 <= len);
        if (!fullt) {
            #pragma unroll
            for (int kq2 = 0; kq2 < 2; ++kq2)
                #pragma unroll
                for (int gq = 0; gq < 2; ++gq) {
                    int qg = qbase + gq * 16 + fr;
                    #pragma unroll
                    for (int j = 0; j < 4; ++j) {
                        int kg = kbase + kq2 * 16 + fq * 4 + j;
                        s[kq2][gq][j] = (kg <= qg && kg < len) ? s[kq2][gq][j] : -1e30f;
                    }
                }
        }
        #pragma unroll
        for (int kq2 = 0; kq2 < 2; ++kq2)
            #pragma unroll
            for (int gq = 0; gq < 2; ++gq)
                #pragma unroll
                for (int j = 0; j < 4; ++j)
                    s[kq2][gq][j] = exp2_hw(s[kq2][gq][j]);

        bf16x8 pa[2];
        #pragma unroll
        for (int gq = 0; gq < 2; ++gq) {
            u32x4 w;
            w[0] = pack2bf(s[0][gq][0], s[0][gq][1]);
            w[1] = pack2bf(s[0][gq][2], s[0][gq][3]);
            w[2] = pack2bf(s[1][gq][0], s[1][gq][1]);
            w[3] = pack2bf(s[1][gq][2], s[1][gq][3]);
            pa[gq] = __builtin_bit_cast(bf16x8, w);
        }

        if (has_next) write_V(vr, nxt);

        __builtin_amdgcn_s_setprio(1);
        bf16x8 vbr[4];
        #pragma unroll
        for (int n = 0; n < 4; ++n) {
            int vr2 = n * 16 + fr;
            vbr[n] = *reinterpret_cast<const bf16x8*>(
                &Vts[cur][vr2 * 64 + ((t * 32 + fq * 8) ^ ((fr & 7) << 3))]);
        }
        #pragma unroll
        for (int gq = 0; gq < 2; ++gq) {
            lacc[gq] = __builtin_amdgcn_mfma_f32_16x16x32_bf16(pa[gq], ones, lacc[gq], 0, 0, 0);
            #pragma unroll
            for (int n = 0; n < 4; ++n)
                o_acc[gq][n] = __builtin_amdgcn_mfma_f32_16x16x32_bf16(pa[gq], vbr[n], o_acc[gq][n], 0, 0, 0);
        }
        __builtin_amdgcn_s_setprio(0);

        __syncthreads();
    }

    // combine k-team partials (pure addition; fixed-base softmax)
    __syncthreads();
    float* ocomb = reinterpret_cast<float*>(&Ks[0][0]);
    float* lcomb = ocomb + 64 * 68;
    if (t == 1) {
        #pragma unroll
        for (int gq = 0; gq < 2; ++gq)
            #pragma unroll
            for (int j = 0; j < 4; ++j) {
                int ql = u * 32 + gq * 16 + fq * 4 + j;
                #pragma unroll
                for (int n = 0; n < 4; ++n)
                    ocomb[ql * 68 + n * 16 + fr] = o_acc[gq][n][j];
                if (fr == 0) lcomb[ql] = lacc[gq][j];
            }
    }
    __syncthreads();
    if (t == 0) {
        #pragma unroll
        for (int gq = 0; gq < 2; ++gq)
            #pragma unroll
            for (int j = 0; j < 4; ++j) {
                int ql = u * 32 + gq * 16 + fq * 4 + j;
                float inv = 1.f / (lacc[gq][j] + lcomb[ql]);
                int row = qt * 64 + ql;
                #pragma unroll
                for (int n = 0; n < 4; ++n) {
                    float osum = o_acc[gq][n][j] + ocomb[ql * 68 + n * 16 + fr];
                    Ob[(size_t)(b * 2048 + row) * 1024 + h * 64 + n * 16 + fr] = f2bf(osum * inv);
                }
            }
    }
}

// ------------------------------ launch -------------------------------------
extern "C" void kernel_launch(void* const* d_in, const int* in_sizes, int n_in,
                              void* d_out, int out_size, void* d_ws, size_t ws_size,
                              hipStream_t stream) {
    const float* xq_f = (const float*)d_in[0];
    const float* xk_f = (const float*)d_in[1];
    const int* kpm = (const int*)d_in[3];
    const float* Wq = (const float*)d_in[4];
    const float* bq = (const float*)d_in[5];
    const float* Wk = (const float*)d_in[6];
    const float* bk = (const float*)d_in[7];
    const float* Wv = (const float*)d_in[8];
    const float* bv = (const float*)d_in[9];
    const float* Wo = (const float*)d_in[10];
    const float* bo = (const float*)d_in[11];

    u16* ws = (u16*)d_ws;
    u16* xq = ws;                 // unused (layout stability)
    u16* xk = xq + 4194304;
    u16* wq = xk + 4194304;
    u16* wk = wq + 1048576;
    u16* wv = wk + 1048576;
    u16* wo = wv + 1048576;
    u16* qb = wo + 1048576;
    u16* kb2 = qb + 4194304;
    u16* vb2 = kb2 + 4194304;
    u16* ag = vb2 + 4194304;
    int* lens = (int*)(ag + 4194304);

    cvt_all<<<4098, 256, 0, stream>>>(Wq, Wk, Wv, Wo, wq, wk, wv, wo, kpm, lens);

    gemm_qkv<<<768, 256, 0, stream>>>(xq_f, xk_f, wq, wk, wv,
                                      bq, bk, bv, qb, kb2, vb2);

    attn_fwd<<<1024, 256, 0, stream>>>(qb, kb2, vb2, lens, ag);

    gemm_out<<<512, 256, 0, stream>>>(ag, wo, bo, (float*)d_out);
}

// Round 24
// 98.140 us; speedup vs baseline: 1.0815x; 1.0815x over previous
//
#include <hip/hip_runtime.h>
#include <hip/hip_bf16.h>

// ---------------------------------------------------------------------------
// Self-attention MH: B=2, QL=KL=2048, D=1024, H=16, E=64.
// R24: revert to R22 (best measured, 98.7us).
//      cvt_all: full x+W f32->bf16 + lens. gemm_qkv: bf16 single-buffer
//      BK=64, 3 blocks/CU, XCD 2x4 remap. gemm_out: dbuf single-barrier.
//      attn: grid 1024 / 4 blocks/CU, 2x2 wave decomposition, swapped QK^T
//      in-reg P, fixed-base exp2 softmax, l via MFMA-ones, XCD-locality
//      remap, padded combine scratch.
// ---------------------------------------------------------------------------

typedef __bf16 bf16x8 __attribute__((ext_vector_type(8)));
typedef float f32x4 __attribute__((ext_vector_type(4)));
typedef unsigned int u32x4 __attribute__((ext_vector_type(4)));
typedef unsigned short u16;
typedef unsigned int u32;

#define GLOBAL_AS __attribute__((address_space(1)))
#define LDS_AS __attribute__((address_space(3)))

static __device__ __forceinline__ u16 f2bf(float f) {
    __hip_bfloat16 h = __float2bfloat16(f);
    return __builtin_bit_cast(u16, h);
}
static __device__ __forceinline__ u32 pack2bf(float a, float b) {
    return (u32)f2bf(a) | ((u32)f2bf(b) << 16);
}
static __device__ __forceinline__ float exp2_hw(float x) {
    return __builtin_amdgcn_exp2f(x);   // v_exp_f32 (base-2)
}

// --------------- fused f32 -> bf16 (+ padding-length blocks) ---------------
__global__ void cvt_all(const float* __restrict__ xq_f, const float* __restrict__ xk_f,
                        const float* __restrict__ wq_f, const float* __restrict__ wk_f,
                        const float* __restrict__ wv_f, const float* __restrict__ wo_f,
                        u16* __restrict__ xq, u16* __restrict__ xk,
                        u16* __restrict__ wq, u16* __restrict__ wk,
                        u16* __restrict__ wv, u16* __restrict__ wo,
                        const int* __restrict__ kpm, int* __restrict__ lens) {
    int blk = blockIdx.x;
    if (blk >= 12288) {
        const int b = blk - 12288, tid = threadIdx.x;
        int cnt = 0;
        #pragma unroll
        for (int i = 0; i < 8; ++i) cnt += (kpm[b * 2048 + i * 256 + tid] == 0) ? 1 : 0;
        #pragma unroll
        for (int off = 32; off; off >>= 1) cnt += __shfl_down(cnt, off);
        __shared__ int wsum[4];
        if ((tid & 63) == 0) wsum[tid >> 6] = cnt;
        __syncthreads();
        if (tid == 0) lens[b] = wsum[0] + wsum[1] + wsum[2] + wsum[3];
        return;
    }
    const float* s; u16* d; int i;
    if (blk < 4096)      { s = xq_f; d = xq; i = blk * 256 + threadIdx.x; }
    else if (blk < 8192) { s = xk_f; d = xk; i = (blk - 4096) * 256 + threadIdx.x; }
    else {
        int wsel = (blk - 8192) >> 10;
        i = ((blk - 8192) & 1023) * 256 + threadIdx.x;
        if (wsel == 0)      { s = wq_f; d = wq; }
        else if (wsel == 1) { s = wk_f; d = wk; }
        else if (wsel == 2) { s = wv_f; d = wv; }
        else                { s = wo_f; d = wo; }
    }
    float4 v = reinterpret_cast<const float4*>(s)[i];
    ushort4 o;
    o.x = f2bf(v.x); o.y = f2bf(v.y); o.z = f2bf(v.z); o.w = f2bf(v.w);
    reinterpret_cast<ushort4*>(d)[i] = o;
}

// ------------------------------ GEMM body: C = (A*B^T + bias)*scale --------
// Single-buffer 2-barrier variant (gemm_qkv; 3 blocks/CU).
template<int OUT_F32, int BM, int BN>
__device__ __forceinline__
void gemm_body(const u16* __restrict__ A, const u16* __restrict__ Bw,
               const float* __restrict__ bias, void* __restrict__ Cout,
               int N, int K, float scale, int bx, int by) {
    constexpr int MREP = BM / 32, NREP = BN / 32;
    constexpr int ACH = BM / 8, TCH = ACH + BN / 8;   // 1KB chunks (8 rows each)
    constexpr int CPW = TCH / 4;
    __shared__ __attribute__((aligned(16))) u16 aS[BM * 64];
    __shared__ __attribute__((aligned(16))) u16 bS[BN * 64];
    const int tid = threadIdx.x, wave = tid >> 6, lane = tid & 63;
    const int m0 = by * BM, n0 = bx * BN;
    const int wr = wave >> 1, wc = wave & 1;
    const int fr = lane & 15, fq = lane >> 4;
    const int swz_col = (((lane & 7) ^ (lane >> 3)) * 8);   // pre-swizzled src col
    const int rsw = (fr & 7) << 3;                          // read-side XOR

    f32x4 acc[MREP][NREP] = {};

    for (int k0 = 0; k0 < K; k0 += 64) {
        #pragma unroll
        for (int i = 0; i < CPW; ++i) {
            int chunk = wave * CPW + i;
            const u16* gsrc; u16* ldst;
            if (chunk < ACH) {
                int row = chunk * 8 + (lane >> 3);
                gsrc = A + (size_t)(m0 + row) * K + k0 + swz_col;
                ldst = aS + chunk * 512;
            } else {
                int row = (chunk - ACH) * 8 + (lane >> 3);
                gsrc = Bw + (size_t)(n0 + row) * K + k0 + swz_col;
                ldst = bS + (chunk - ACH) * 512;
            }
            __builtin_amdgcn_global_load_lds((GLOBAL_AS void*)gsrc,
                                             (LDS_AS void*)ldst, 16, 0, 0);
        }
        __syncthreads();
        bf16x8 af[MREP][2], bfr[NREP][2];
        #pragma unroll
        for (int m = 0; m < MREP; ++m)
            #pragma unroll
            for (int h = 0; h < 2; ++h)
                af[m][h] = *reinterpret_cast<const bf16x8*>(
                    &aS[(wr * (BM / 2) + m * 16 + fr) * 64 + ((h * 32 + fq * 8) ^ rsw)]);
        #pragma unroll
        for (int n = 0; n < NREP; ++n)
            #pragma unroll
            for (int h = 0; h < 2; ++h)
                bfr[n][h] = *reinterpret_cast<const bf16x8*>(
                    &bS[(wc * (BN / 2) + n * 16 + fr) * 64 + ((h * 32 + fq * 8) ^ rsw)]);
        __builtin_amdgcn_s_setprio(1);
        #pragma unroll
        for (int m = 0; m < MREP; ++m)
            #pragma unroll
            for (int n = 0; n < NREP; ++n) {
                acc[m][n] = __builtin_amdgcn_mfma_f32_16x16x32_bf16(af[m][0], bfr[n][0], acc[m][n], 0, 0, 0);
                acc[m][n] = __builtin_amdgcn_mfma_f32_16x16x32_bf16(af[m][1], bfr[n][1], acc[m][n], 0, 0, 0);
            }
        __builtin_amdgcn_s_setprio(0);
        __syncthreads();
    }

    #pragma unroll
    for (int n = 0; n < NREP; ++n) {
        int col = n0 + wc * (BN / 2) + n * 16 + fr;
        float bv = bias[col];
        #pragma unroll
        for (int m = 0; m < MREP; ++m) {
            #pragma unroll
            for (int j = 0; j < 4; ++j) {
                int row = m0 + wr * (BM / 2) + m * 16 + fq * 4 + j;
                float v = (acc[m][n][j] + bv) * scale;
                if (OUT_F32)
                    reinterpret_cast<float*>(Cout)[(size_t)row * N + col] = v;
                else
                    reinterpret_cast<u16*>(Cout)[(size_t)row * N + col] = f2bf(v);
            }
        }
    }
}

// Double-buffered single-barrier variant (gemm_out).
template<int OUT_F32, int BM, int BN>
__device__ __forceinline__
void gemm_body_dbuf(const u16* __restrict__ A, const u16* __restrict__ Bw,
                    const float* __restrict__ bias, void* __restrict__ Cout,
                    int N, int K, float scale, int bx, int by) {
    constexpr int MREP = BM / 32, NREP = BN / 32;
    constexpr int ACH = BM / 8, TCH = ACH + BN / 8;
    constexpr int CPW = TCH / 4;
    __shared__ __attribute__((aligned(16))) u16 aS[2][BM * 64];
    __shared__ __attribute__((aligned(16))) u16 bS[2][BN * 64];
    const int tid = threadIdx.x, wave = tid >> 6, lane = tid & 63;
    const int m0 = by * BM, n0 = bx * BN;
    const int wr = wave >> 1, wc = wave & 1;
    const int fr = lane & 15, fq = lane >> 4;
    const int swz_col = (((lane & 7) ^ (lane >> 3)) * 8);
    const int rsw = (fr & 7) << 3;

    f32x4 acc[MREP][NREP] = {};

    auto stage = [&](int k0, int buf) {
        #pragma unroll
        for (int i = 0; i < CPW; ++i) {
            int chunk = wave * CPW + i;
            const u16* gsrc; u16* ldst;
            if (chunk < ACH) {
                int row = chunk * 8 + (lane >> 3);
                gsrc = A + (size_t)(m0 + row) * K + k0 + swz_col;
                ldst = &aS[buf][chunk * 512];
            } else {
                int row = (chunk - ACH) * 8 + (lane >> 3);
                gsrc = Bw + (size_t)(n0 + row) * K + k0 + swz_col;
                ldst = &bS[buf][(chunk - ACH) * 512];
            }
            __builtin_amdgcn_global_load_lds((GLOBAL_AS void*)gsrc,
                                             (LDS_AS void*)ldst, 16, 0, 0);
        }
    };

    stage(0, 0);
    __syncthreads();
    int cur = 0;

    for (int k0 = 0; k0 < K; k0 += 64) {
        if (k0 + 64 < K) stage(k0 + 64, cur ^ 1);

        bf16x8 af[MREP][2], bfr[NREP][2];
        #pragma unroll
        for (int m = 0; m < MREP; ++m)
            #pragma unroll
            for (int h = 0; h < 2; ++h)
                af[m][h] = *reinterpret_cast<const bf16x8*>(
                    &aS[cur][(wr * (BM / 2) + m * 16 + fr) * 64 + ((h * 32 + fq * 8) ^ rsw)]);
        #pragma unroll
        for (int n = 0; n < NREP; ++n)
            #pragma unroll
            for (int h = 0; h < 2; ++h)
                bfr[n][h] = *reinterpret_cast<const bf16x8*>(
                    &bS[cur][(wc * (BN / 2) + n * 16 + fr) * 64 + ((h * 32 + fq * 8) ^ rsw)]);
        __builtin_amdgcn_s_setprio(1);
        #pragma unroll
        for (int m = 0; m < MREP; ++m)
            #pragma unroll
            for (int n = 0; n < NREP; ++n) {
                acc[m][n] = __builtin_amdgcn_mfma_f32_16x16x32_bf16(af[m][0], bfr[n][0], acc[m][n], 0, 0, 0);
                acc[m][n] = __builtin_amdgcn_mfma_f32_16x16x32_bf16(af[m][1], bfr[n][1], acc[m][n], 0, 0, 0);
            }
        __builtin_amdgcn_s_setprio(0);
        __syncthreads();
        cur ^= 1;
    }

    #pragma unroll
    for (int n = 0; n < NREP; ++n) {
        int col = n0 + wc * (BN / 2) + n * 16 + fr;
        float bv = bias[col];
        #pragma unroll
        for (int m = 0; m < MREP; ++m) {
            #pragma unroll
            for (int j = 0; j < 4; ++j) {
                int row = m0 + wr * (BM / 2) + m * 16 + fq * 4 + j;
                float v = (acc[m][n][j] + bv) * scale;
                if (OUT_F32)
                    reinterpret_cast<float*>(Cout)[(size_t)row * N + col] = v;
                else
                    reinterpret_cast<u16*>(Cout)[(size_t)row * N + col] = f2bf(v);
            }
        }
    }
}

// Fused Q/K/V projection; Q pre-scaled by log2(e)/32 (exp2-domain softmax).
// Linear grid 768 = 3 blocks/CU; XCD g = id&7 owns M-rows (g>>1)*1024..+1024,
// N-cols (g&1)*512..+512 for all z.
__global__ __launch_bounds__(256, 3)
void gemm_qkv(const u16* __restrict__ xq, const u16* __restrict__ xk,
              const u16* __restrict__ wq, const u16* __restrict__ wk,
              const u16* __restrict__ wv,
              const float* __restrict__ bq, const float* __restrict__ bk,
              const float* __restrict__ bv,
              u16* __restrict__ qb, u16* __restrict__ kb, u16* __restrict__ vb) {
    const int id = blockIdx.x;
    const int g = id & 7, s = id >> 3;          // XCD, slot 0..95
    const int z = s >> 5;                        // 0..2 (CU-mates differ in z)
    const int xl = (s >> 3) & 3, byl = s & 7;
    const int bx = (g & 1) * 4 + xl;
    const int by = (g >> 1) * 8 + byl;
    const u16* A = (z == 0) ? xq : xk;
    const u16* W = (z == 0) ? wq : (z == 1) ? wk : wv;
    const float* bias = (z == 0) ? bq : (z == 1) ? bk : bv;
    u16* C = (z == 0) ? qb : (z == 1) ? kb : vb;
    const float scale = (z == 0) ? 0.0450842200f : 1.0f;   // log2e/32
    gemm_body<0, 128, 128>(A, W, bias, C, 1024, 1024, scale, bx, by);
}

// Out projection: 64x128 tiles, linear grid 512, same 2x4 XCD split, dbuf.
__global__ __launch_bounds__(256, 2)
void gemm_out(const u16* __restrict__ A, const u16* __restrict__ Bw,
              const float* __restrict__ bias, float* __restrict__ Cout) {
    const int id = blockIdx.x;
    const int g = id & 7, s = id >> 3;          // slot 0..63
    const int xl = s & 3, byl = s >> 2;         // byl 0..15
    const int bx = (g & 1) * 4 + xl;
    const int by = (g >> 1) * 16 + byl;
    gemm_body_dbuf<1, 64, 128>(A, Bw, bias, Cout, 1024, 1024, 1.0f, bx, by);
}

// ------------------------------ flash attention ----------------------------
// Grid 1024 linear; XCD-locality remap + per-CU qt balance.
// Wave (t,u): q in [qt*64+32u, +32), k-half t of each tile; per wave-tile
// 4 K + 4 V b128 reads, 8 QK + 8 PV + 2 l MFMA. Swapped QK^T, in-register P
// via k'-perm; fixed-base exp2 softmax => k-team partials combine by addition
// once per block via padded LDS scratch (stride 68 f32 — conflict-free).
__global__ __launch_bounds__(256, 4)
void attn_fwd(const u16* __restrict__ Qb, const u16* __restrict__ Kb,
              const u16* __restrict__ Vb, const int* __restrict__ lens,
              u16* __restrict__ Ob) {
    __shared__ __attribute__((aligned(16))) u16 Ks[2][64 * 64];
    __shared__ __attribute__((aligned(16))) u16 Vts[2][64 * 64];
    const int tid = threadIdx.x, wave = tid >> 6, lane = tid & 63;
    const int id = blockIdx.x;
    const int bh = (id & 7) * 4 + ((id >> 3) & 3);
    const int k5 = id >> 5;
    const int g = k5 >> 3, x8 = k5 & 7;
    const int qt = (g == 0) ? x8 : (g == 1) ? 31 - x8 : (g == 2) ? 16 + x8 : 15 - x8;
    const int b = bh >> 4, h = bh & 15;
    const int fr = lane & 15, fq = lane >> 4;
    const int t = wave >> 1;                    // k-half team
    const int u = wave & 1;                     // q-half
    const int qbase = qt * 64 + u * 32;
    const int len = lens[b];
    const int nt = min(qt + 1, (len + 63) >> 6);

    bf16x8 qa[2][2];
    #pragma unroll
    for (int gq = 0; gq < 2; ++gq) {
        const size_t qoff = (size_t)(b * 2048 + qbase + gq * 16 + fr) * 1024 + h * 64 + fq * 8;
        qa[gq][0] = *reinterpret_cast<const bf16x8*>(Qb + qoff);
        qa[gq][1] = *reinterpret_cast<const bf16x8*>(Qb + qoff + 32);
    }

    bf16x8 ones;
    #pragma unroll
    for (int i = 0; i < 8; ++i) ones[i] = __builtin_bit_cast(__bf16, (u16)0x3F80);

    f32x4 o_acc[2][4] = {};   // [q-group][e-frag], k-partial
    f32x4 lacc[2] = {};       // [q-group], k-partial

    const int e8 = tid >> 5;                       // 0..7 (8 e-rows each)
    const int c2 = tid & 31;                       // 0..31
    const int kp = 2 * c2;
    const int vhalf = kp >> 5, r5 = kp & 31;
    const int fqv = r5 >> 3, nv = (r5 >> 2) & 1, jv = r5 & 3;
    const int k_src = vhalf * 32 + nv * 16 + fqv * 4 + jv;
    const int kswz_col = (((lane & 7) ^ (lane >> 3)) * 8);

    auto issue_K = [&](int kt, int buf) {
        #pragma unroll
        for (int i = 0; i < 2; ++i) {
            int chunk = wave * 2 + i;
            int krow = chunk * 8 + (lane >> 3);
            const u16* gk = Kb + (size_t)(b * 2048 + kt * 64 + krow) * 1024 + h * 64 + kswz_col;
            __builtin_amdgcn_global_load_lds((GLOBAL_AS void*)gk,
                                             (LDS_AS void*)(&Ks[buf][chunk * 512]), 16, 0, 0);
        }
    };
    auto load_V = [&](int kt, ushort4* r) {
        const u16* b1 = Vb + (size_t)(b * 2048 + kt * 64 + k_src) * 1024 + h * 64 + e8 * 8;
        r[0] = reinterpret_cast<const ushort4*>(b1)[0];
        r[1] = reinterpret_cast<const ushort4*>(b1 + 4)[0];
        r[2] = reinterpret_cast<const ushort4*>(b1 + 1024)[0];        // k_src+1
        r[3] = reinterpret_cast<const ushort4*>(b1 + 1024 + 4)[0];
    };
    auto write_V = [&](const ushort4* r, int buf) {
        u32* vbase = reinterpret_cast<u32*>(&Vts[buf][0]);
        const u16* lo16 = reinterpret_cast<const u16*>(&r[0]);  // e-run of k_src
        const u16* hi16 = reinterpret_cast<const u16*>(&r[2]);  // e-run of k_src+1
        #pragma unroll
        for (int i = 0; i < 8; ++i) {
            u32 w = (u32)lo16[i] | ((u32)hi16[i] << 16);
            vbase[(e8 * 8 + i) * 32 + (c2 ^ (i << 2))] = w;
        }
    };

    {
        ushort4 vr[4];
        issue_K(0, 0);
        load_V(0, vr);
        write_V(vr, 0);
    }
    __syncthreads();

    for (int kt = 0; kt < nt; ++kt) {
        const int k0 = kt * 64;
        const int kbase = k0 + t * 32;
        const int cur = kt & 1, nxt = cur ^ 1;
        const bool has_next = (kt + 1 < nt);

        ushort4 vr[4];
        if (has_next) {
            issue_K(kt + 1, nxt);
            load_V(kt + 1, vr);
        }

        // S^T = K Q^T for own (k-half, q-half): s[kq2][gq]
        f32x4 s[2][2] = {};
        __builtin_amdgcn_s_setprio(1);
        #pragma unroll
        for (int kq2 = 0; kq2 < 2; ++kq2) {
            int kr = t * 32 + kq2 * 16 + fr;
            int sw = (fr & 7) << 3;
            bf16x8 kb0 = *reinterpret_cast<const bf16x8*>(&Ks[cur][kr * 64 + ((fq * 8) ^ sw)]);
            bf16x8 kb1 = *reinterpret_cast<const bf16x8*>(&Ks[cur][kr * 64 + ((32 + fq * 8) ^ sw)]);
            #pragma unroll
            for (int gq = 0; gq < 2; ++gq) {
                s[kq2][gq] = __builtin_amdgcn_mfma_f32_16x16x32_bf16(kb0, qa[gq][0], s[kq2][gq], 0, 0, 0);
                s[kq2][gq] = __builtin_amdgcn_mfma_f32_16x16x32_bf16(kb1, qa[gq][1], s[kq2][gq], 0, 0, 0);
            }
        }
        __builtin_amdgcn_s_setprio(0);

        // mask (boundary only): lane (fq,j) -> k-row, fr -> q (per q-group)
        const bool fullt = (kbase + 31 <= qbase) && (kbase + 32 <= len);
        if (!fullt) {
            #pragma unroll
            for (int kq2 = 0; kq2 < 2; ++kq2)
                #pragma unroll
                for (int gq = 0; gq < 2; ++gq) {
                    int qg = qbase + gq * 16 + fr;
                    #pragma unroll
                    for (int j = 0; j < 4; ++j) {
                        int kg = kbase + kq2 * 16 + fq * 4 + j;
                        s[kq2][gq][j] = (kg <= qg && kg < len) ? s[kq2][gq][j] : -1e30f;
                    }
                }
        }
        #pragma unroll
        for (int kq2 = 0; kq2 < 2; ++kq2)
            #pragma unroll
            for (int gq = 0; gq < 2; ++gq)
                #pragma unroll
                for (int j = 0; j < 4; ++j)
                    s[kq2][gq][j] = exp2_hw(s[kq2][gq][j]);

        // pack P in-register: pa[gq] elem m: (m<4) ? s[0][gq][m] : s[1][gq][m-4]
        bf16x8 pa[2];
        #pragma unroll
        for (int gq = 0; gq < 2; ++gq) {
            u32x4 w;
            w[0] = pack2bf(s[0][gq][0], s[0][gq][1]);
            w[1] = pack2bf(s[0][gq][2], s[0][gq][3]);
            w[2] = pack2bf(s[1][gq][0], s[1][gq][1]);
            w[3] = pack2bf(s[1][gq][2], s[1][gq][3]);
            pa[gq] = __builtin_bit_cast(bf16x8, w);
        }

        // next tile's V regs -> LDS before PV (ds_writes retire under MFMAs)
        if (has_next) write_V(vr, nxt);

        // O += P V over own k'-half; l += P * ones
        __builtin_amdgcn_s_setprio(1);
        bf16x8 vbr[4];
        #pragma unroll
        for (int n = 0; n < 4; ++n) {
            int vr2 = n * 16 + fr;
            vbr[n] = *reinterpret_cast<const bf16x8*>(
                &Vts[cur][vr2 * 64 + ((t * 32 + fq * 8) ^ ((fr & 7) << 3))]);
        }
        #pragma unroll
        for (int gq = 0; gq < 2; ++gq) {
            lacc[gq] = __builtin_amdgcn_mfma_f32_16x16x32_bf16(pa[gq], ones, lacc[gq], 0, 0, 0);
            #pragma unroll
            for (int n = 0; n < 4; ++n)
                o_acc[gq][n] = __builtin_amdgcn_mfma_f32_16x16x32_bf16(pa[gq], vbr[n], o_acc[gq][n], 0, 0, 0);
        }
        __builtin_amdgcn_s_setprio(0);

        __syncthreads();
    }

    // ---- combine k-team partials (pure addition; fixed-base softmax) ----
    __syncthreads();                       // all tile reads done; reuse LDS
    float* ocomb = reinterpret_cast<float*>(&Ks[0][0]);
    float* lcomb = ocomb + 64 * 68;
    if (t == 1) {
        #pragma unroll
        for (int gq = 0; gq < 2; ++gq)
            #pragma unroll
            for (int j = 0; j < 4; ++j) {
                int ql = u * 32 + gq * 16 + fq * 4 + j;
                #pragma unroll
                for (int n = 0; n < 4; ++n)
                    ocomb[ql * 68 + n * 16 + fr] = o_acc[gq][n][j];
                if (fr == 0) lcomb[ql] = lacc[gq][j];
            }
    }
    __syncthreads();
    if (t == 0) {
        #pragma unroll
        for (int gq = 0; gq < 2; ++gq)
            #pragma unroll
            for (int j = 0; j < 4; ++j) {
                int ql = u * 32 + gq * 16 + fq * 4 + j;
                float inv = 1.f / (lacc[gq][j] + lcomb[ql]);
                int row = qt * 64 + ql;
                #pragma unroll
                for (int n = 0; n < 4; ++n) {
                    float osum = o_acc[gq][n][j] + ocomb[ql * 68 + n * 16 + fr];
                    Ob[(size_t)(b * 2048 + row) * 1024 + h * 64 + n * 16 + fr] = f2bf(osum * inv);
                }
            }
    }
}

// ------------------------------ launch -------------------------------------
extern "C" void kernel_launch(void* const* d_in, const int* in_sizes, int n_in,
                              void* d_out, int out_size, void* d_ws, size_t ws_size,
                              hipStream_t stream) {
    const float* xq_f = (const float*)d_in[0];
    const float* xk_f = (const float*)d_in[1];
    const int* kpm = (const int*)d_in[3];
    const float* Wq = (const float*)d_in[4];
    const float* bq = (const float*)d_in[5];
    const float* Wk = (const float*)d_in[6];
    const float* bk = (const float*)d_in[7];
    const float* Wv = (const float*)d_in[8];
    const float* bv = (const float*)d_in[9];
    const float* Wo = (const float*)d_in[10];
    const float* bo = (const float*)d_in[11];

    u16* ws = (u16*)d_ws;
    u16* xq = ws;
    u16* xk = xq + 4194304;
    u16* wq = xk + 4194304;
    u16* wk = wq + 1048576;
    u16* wv = wk + 1048576;
    u16* wo = wv + 1048576;
    u16* qb = wo + 1048576;
    u16* kb2 = qb + 4194304;
    u16* vb2 = kb2 + 4194304;
    u16* ag = vb2 + 4194304;
    int* lens = (int*)(ag + 4194304);

    cvt_all<<<12290, 256, 0, stream>>>(xq_f, xk_f, Wq, Wk, Wv, Wo,
                                       xq, xk, wq, wk, wv, wo, kpm, lens);

    gemm_qkv<<<768, 256, 0, stream>>>(xq, xk, wq, wk, wv,
                                      bq, bk, bv, qb, kb2, vb2);

    attn_fwd<<<1024, 256, 0, stream>>>(qb, kb2, vb2, lens, ag);

    gemm_out<<<512, 256, 0, stream>>>(ag, wo, bo, (float*)d_out);
}